// Round 1
// baseline (514.207 us; speedup 1.0000x reference)
//
#include <hip/hip_runtime.h>
#include <math.h>

// BridgeNodes: per group g, out[g] = where(sigmoid(A_g A_g^T) < 0.6, 0, sigmoid(...))
// G=4, N=4096, F=128, fp32 in/out. Round 1: accurate fp32 vector kernel
// (no fp32 MFMA on CDNA4). 64x64 output tile per 256-thread block, full
// K=128 staged in LDS as [k][m] (transposed on load).

constexpr int GROUPS = 4;
constexpr int N = 4096;
constexpr int F = 128;
constexpr int BT = 64;          // output tile edge
constexpr float THRESH = 0.6f;

__global__ __launch_bounds__(256, 2)
void bridge_nodes_kernel(const float* __restrict__ nodes, float* __restrict__ out) {
    // LDS: [k][m] layout so the k-loop reads contiguous float4 fragments.
    __shared__ float As[F][BT];   // 32 KB
    __shared__ float Bs[F][BT];   // 32 KB

    const int g  = blockIdx.z;
    const int bm = blockIdx.y;    // row tile
    const int bn = blockIdx.x;    // col tile
    const float* __restrict__ base = nodes + (size_t)g * N * F;

    const int tid = threadIdx.x;

    // ---- Stage A-tile (rows bm*64..+63) and B-tile (rows bn*64..+63) ----
    // Lane mapping: r = tid&63 (consecutive lanes -> consecutive m), c0 = tid>>6.
    // LDS write As[4c+j][r]: addr = (4c+j)*64 + r -> consecutive lanes hit
    // consecutive banks: conflict-free. Global reads are strided (lane -> row)
    // but the 8 MB input is L2/L3-resident and reused by 64 blocks per row.
    {
        const int r  = tid & 63;
        const int c0 = tid >> 6;   // 0..3
        const float* arow = base + (size_t)(bm * BT + r) * F;
        const float* brow = base + (size_t)(bn * BT + r) * F;
#pragma unroll
        for (int i = 0; i < 8; ++i) {
            const int c = c0 + (i << 2);           // float4 index 0..31
            const float4 av = *(const float4*)(arow + (c << 2));
            const float4 bv = *(const float4*)(brow + (c << 2));
            As[4 * c + 0][r] = av.x;
            As[4 * c + 1][r] = av.y;
            As[4 * c + 2][r] = av.z;
            As[4 * c + 3][r] = av.w;
            Bs[4 * c + 0][r] = bv.x;
            Bs[4 * c + 1][r] = bv.y;
            Bs[4 * c + 2][r] = bv.z;
            Bs[4 * c + 3][r] = bv.w;
        }
    }
    __syncthreads();

    // ---- 4x4 per-thread accumulation over K=128 ----
    const int tx = tid & 15;      // col quad
    const int ty = tid >> 4;      // row quad
    float acc[4][4] = {};

#pragma unroll 8
    for (int k = 0; k < F; ++k) {
        const float4 a = *(const float4*)&As[k][ty << 2];  // 16-lane broadcast
        const float4 b = *(const float4*)&Bs[k][tx << 2];  // 2 lanes/bank: free
        const float aa[4] = {a.x, a.y, a.z, a.w};
        const float bb[4] = {b.x, b.y, b.z, b.w};
#pragma unroll
        for (int i = 0; i < 4; ++i)
#pragma unroll
            for (int j = 0; j < 4; ++j)
                acc[i][j] = fmaf(aa[i], bb[j], acc[i][j]);
    }

    // ---- Epilogue: sigmoid + threshold, coalesced float4 stores ----
    const size_t outg = (size_t)g * N * N;
#pragma unroll
    for (int i = 0; i < 4; ++i) {
        const int row = bm * BT + (ty << 2) + i;
        float* o = out + outg + (size_t)row * N + bn * BT + (tx << 2);
        float4 v;
        {
            const float s = 1.0f / (1.0f + expf(-acc[i][0]));
            v.x = (s < THRESH) ? 0.0f : s;
        }
        {
            const float s = 1.0f / (1.0f + expf(-acc[i][1]));
            v.y = (s < THRESH) ? 0.0f : s;
        }
        {
            const float s = 1.0f / (1.0f + expf(-acc[i][2]));
            v.z = (s < THRESH) ? 0.0f : s;
        }
        {
            const float s = 1.0f / (1.0f + expf(-acc[i][3]));
            v.w = (s < THRESH) ? 0.0f : s;
        }
        *(float4*)o = v;
    }
}

extern "C" void kernel_launch(void* const* d_in, const int* in_sizes, int n_in,
                              void* d_out, int out_size, void* d_ws, size_t ws_size,
                              hipStream_t stream) {
    const float* nodes = (const float*)d_in[0];
    float* out = (float*)d_out;
    dim3 grid(N / BT, N / BT, GROUPS);   // 64 x 64 x 4 = 16384 blocks
    dim3 block(256);
    bridge_nodes_kernel<<<grid, block, 0, stream>>>(nodes, out);
}

// Round 2
// 357.603 us; speedup vs baseline: 1.4379x; 1.4379x over previous
//
#include <hip/hip_runtime.h>
#include <math.h>

// BridgeNodes R2: exploit symmetry of sigmoid(A A^T) — compute only upper-tri
// 128x128 tiles (528/1024), mirror off-diag tiles via LDS transpose.
// 8x8 acc per thread in split 4+4 quadrants: 64 FMA per 4 ds_read_b128.
// Numerics bitwise-identical to R1 (same ascending-k fmaf chain, same expf),
// so absmax stays 0.00390625.

constexpr int GROUPS = 4;
constexpr int N = 4096;
constexpr int F = 128;
constexpr int BT = 128;                          // output tile edge
constexpr int KS = 32;                           // K chunk staged in LDS
constexpr int TILES = N / BT;                    // 32
constexpr int PAIRS = TILES * (TILES + 1) / 2;   // 528
constexpr int LDA = BT + 4;                      // 132: pad breaks bank aliasing, keeps 16B align
constexpr float THRESH = 0.6f;

__device__ __forceinline__ int row_start(int r) { // linear index of pair (r, r)
    return r * TILES - (r * (r - 1)) / 2;
}

__global__ __launch_bounds__(256, 4)
void bridge_nodes_kernel(const float* __restrict__ nodes, float* __restrict__ out) {
    __shared__ float Smem[64 * LDA];             // 33792 B; As+Bs, reused as T
    float* As = Smem;                            // [KS][LDA]
    float* Bs = Smem + KS * LDA;                 // [KS][LDA]

    const int g = blockIdx.y;
    const int t = blockIdx.x;

    // t -> (bm, bn), bm <= bn, row-major upper-triangle enumeration
    int bm = (int)((2 * TILES + 1
                    - sqrtf((float)((2 * TILES + 1) * (2 * TILES + 1) - 8 * t))) * 0.5f);
    bm = bm < 0 ? 0 : (bm > TILES - 1 ? TILES - 1 : bm);
    while (row_start(bm) > t) --bm;
    while (row_start(bm + 1) <= t) ++bm;
    const int bn = bm + (t - row_start(bm));

    const float* __restrict__ base = nodes + (size_t)g * N * F;
    const int tid = threadIdx.x;
    const int tx = tid & 15;                     // col quad (x2 quadrants)
    const int ty = tid >> 4;                     // row quad (x2 quadrants)

    const int srow = tid >> 3;                   // staging: row 0..31 (+32*it)
    const int sf4  = tid & 7;                    // staging: float4 within 32-float chunk

    float acc[2][4][2][4] = {};                  // [rowhalf][i][colhalf][j]

    for (int kc = 0; kc < F / KS; ++kc) {
        // ---- stage K-chunk kc of A-rows and B-rows into [k][m] layout ----
        const int kbase = kc * KS;
#pragma unroll
        for (int it = 0; it < 4; ++it) {
            const int row = srow + 32 * it;      // 0..127
            const float4 av = *(const float4*)(base + (size_t)(bm * BT + row) * F + kbase + sf4 * 4);
            const float4 bv = *(const float4*)(base + (size_t)(bn * BT + row) * F + kbase + sf4 * 4);
            const int k0 = sf4 * 4;
            As[(k0 + 0) * LDA + row] = av.x;
            As[(k0 + 1) * LDA + row] = av.y;
            As[(k0 + 2) * LDA + row] = av.z;
            As[(k0 + 3) * LDA + row] = av.w;
            Bs[(k0 + 0) * LDA + row] = bv.x;
            Bs[(k0 + 1) * LDA + row] = bv.y;
            Bs[(k0 + 2) * LDA + row] = bv.z;
            Bs[(k0 + 3) * LDA + row] = bv.w;
        }
        __syncthreads();

        // ---- 8x8 outer-product accumulation, ascending k (bitwise == R1) ----
#pragma unroll 8
        for (int k = 0; k < KS; ++k) {
            const float4 a0 = *(const float4*)&As[k * LDA + ty * 4];        // 16-lane bcast
            const float4 a1 = *(const float4*)&As[k * LDA + 64 + ty * 4];
            const float4 b0 = *(const float4*)&Bs[k * LDA + tx * 4];        // 2-way: free
            const float4 b1 = *(const float4*)&Bs[k * LDA + 64 + tx * 4];
            const float a[2][4] = {{a0.x, a0.y, a0.z, a0.w}, {a1.x, a1.y, a1.z, a1.w}};
            const float b[2][4] = {{b0.x, b0.y, b0.z, b0.w}, {b1.x, b1.y, b1.z, b1.w}};
#pragma unroll
            for (int ii = 0; ii < 2; ++ii)
#pragma unroll
                for (int i = 0; i < 4; ++i)
#pragma unroll
                    for (int jj = 0; jj < 2; ++jj)
#pragma unroll
                        for (int j = 0; j < 4; ++j)
                            acc[ii][i][jj][j] = fmaf(a[ii][i], b[jj][j], acc[ii][i][jj][j]);
        }
        __syncthreads();                         // safe to restage / reuse as T
    }

    // ---- sigmoid + threshold, in place (precise expf: matches R1/np) ----
#pragma unroll
    for (int ii = 0; ii < 2; ++ii)
#pragma unroll
        for (int i = 0; i < 4; ++i)
#pragma unroll
            for (int jj = 0; jj < 2; ++jj)
#pragma unroll
                for (int j = 0; j < 4; ++j) {
                    const float s = 1.0f / (1.0f + expf(-acc[ii][i][jj][j]));
                    acc[ii][i][jj][j] = (s < THRESH) ? 0.0f : s;
                }

    // ---- direct store of tile (bm, bn): coalesced float4 ----
    const size_t outg = (size_t)g * N * N;
#pragma unroll
    for (int ii = 0; ii < 2; ++ii)
#pragma unroll
        for (int i = 0; i < 4; ++i) {
            const int row = bm * BT + ii * 64 + ty * 4 + i;
            float* o = out + outg + (size_t)row * N + bn * BT;
#pragma unroll
            for (int jj = 0; jj < 2; ++jj) {
                float4 v = {acc[ii][i][jj][0], acc[ii][i][jj][1],
                            acc[ii][i][jj][2], acc[ii][i][jj][3]};
                *(float4*)(o + jj * 64 + tx * 4) = v;
            }
        }

    // ---- mirror store of tile (bn, bm) via LDS transpose (skip diagonal) ----
    if (bm != bn) {
        float* T = Smem;                         // [64][LDA] per pass
        const int rr  = tid >> 2;                // mirror row within pass: 0..63
        const int sub = tid & 3;
#pragma unroll
        for (int h = 0; h < 2; ++h) {            // h = which 64-col half (= jj)
            __syncthreads();
            // write: T[col_within_pass][orig_row], float4 along consecutive rows i
#pragma unroll
            for (int j = 0; j < 4; ++j)
#pragma unroll
                for (int ii = 0; ii < 2; ++ii) {
                    float4 v = {acc[ii][0][h][j], acc[ii][1][h][j],
                                acc[ii][2][h][j], acc[ii][3][h][j]};
                    *(float4*)&T[(4 * tx + j) * LDA + 64 * ii + 4 * ty] = v;
                }
            __syncthreads();
            // read rows of T, store coalesced to mirrored location
            const int mrow = bn * BT + 64 * h + rr;
            float* o = out + outg + (size_t)mrow * N + bm * BT;
            const float* trow = &T[rr * LDA];
#pragma unroll
            for (int it = 0; it < 8; ++it) {
                const int f = it * 4 + sub;      // float4 index 0..31
                *(float4*)(o + f * 4) = *(const float4*)(trow + f * 4);
            }
        }
    }
}

extern "C" void kernel_launch(void* const* d_in, const int* in_sizes, int n_in,
                              void* d_out, int out_size, void* d_ws, size_t ws_size,
                              hipStream_t stream) {
    const float* nodes = (const float*)d_in[0];
    float* out = (float*)d_out;
    dim3 grid(PAIRS, GROUPS);                    // 528 x 4 = 2112 blocks
    dim3 block(256);
    bridge_nodes_kernel<<<grid, block, 0, stream>>>(nodes, out);
}